// Round 6
// baseline (630.180 us; speedup 1.0000x reference)
//
#include <hip/hip_runtime.h>
#include <hip/hip_fp16.h>
#include <math.h>

#define N_NODESC 100000
#define N_EDGESC 1600000
#define E_TOT    1700000   // incl. self loops
#define IN_CH    500
#define KPAD     512
#define D1 64
#define D2 24
#define D2P 32             // xw2 row: 8 heads x (3 classes + src-logit), fp16 = 64B
#define NBKT 391           // dst buckets of 256 nodes
#define CAP  5120          // fixed bucket capacity (mean 4352, sigma ~66 -> 11 sigma)
#define EPB  4096          // edges per partition block
#define NPB  416           // ceil(E_TOT/EPB) partition blocks
#define GEMB 3125          // gemm blocks (100000/32)

typedef __attribute__((ext_vector_type(8))) short short8;
typedef __attribute__((ext_vector_type(4))) float f32x4;

__device__ inline short f2bf(float f) {            // RTNE fp32 -> bf16
    unsigned u = __float_as_uint(f);
    u += 0x7fffu + ((u >> 16) & 1u);
    return (short)(u >> 16);
}
__device__ inline unsigned pkbf(float a, float b) {
    const unsigned ua = __float_as_uint(a) + 0x8000u;
    const unsigned ub = __float_as_uint(b) + 0x8000u;
    return __builtin_amdgcn_perm(ub, ua, 0x07060302u);  // lo16=a_bf, hi16=b_bf
}
__device__ inline float bflo(unsigned u) { return __uint_as_float(u << 16); }
__device__ inline float bfhi(unsigned u) { return __uint_as_float(u & 0xffff0000u); }

// ============ K0: zero bucket cursors + W1 -> bf16 transposed ============
__global__ __launch_bounds__(256) void k_init(int* __restrict__ gcnt,
                                              const float* __restrict__ W1,
                                              short* __restrict__ wT) {
    const int tid = blockIdx.x * 256 + threadIdx.x;     // 64 blocks -> 16384 threads
    for (int i = tid; i < D1 * KPAD; i += 16384) {
        const int n = i >> 9, k = i & (KPAD - 1);
        wT[i] = (k < IN_CH) ? f2bf(W1[k * D1 + n]) : (short)0;
    }
    for (int i = tid; i < NBKT * 32; i += 16384) gcnt[i] = 0;
}

// ============ K1 (fused): edge partition [0..NPB) + gemm1 [NPB..) ============
__global__ __launch_bounds__(256) void k_pg(const int* __restrict__ ei,
                                            int* __restrict__ gcnt,   // stride 32
                                            int* __restrict__ tmp,
                                            const float* __restrict__ x,
                                            const short* __restrict__ wT,
                                            const float* __restrict__ a1s,
                                            const float* __restrict__ a1d,
                                            short* __restrict__ xw1b,
                                            float* __restrict__ al1s,
                                            float* __restrict__ al1d) {
    __shared__ short xs[32 * 520];                     // 33.3 KB; partition path aliases it
    const int t = threadIdx.x;

    if (blockIdx.x < NPB) {                            // ---- partition path ----
        int* hist  = (int*)xs;                         // NBKT ints
        int* lbase = hist + NBKT;                      // NBKT ints
        const int e0 = blockIdx.x * EPB;
        for (int i = t; i < NBKT; i += 256) hist[i] = 0;
        __syncthreads();
        int se[16], de[16], mo[16];
#pragma unroll
        for (int i = 0; i < 16; i++) {
            const int e = e0 + i * 256 + t;
            int s = -1, d = 0;
            if (e < E_TOT) {
                if (e < N_EDGESC) { s = ei[e]; d = ei[N_EDGESC + e]; }
                else { s = d = e - N_EDGESC; }
            }
            se[i] = s; de[i] = d;
            mo[i] = (s >= 0) ? atomicAdd(&hist[d >> 8], 1) : 0;
        }
        __syncthreads();
        for (int i = t; i < NBKT; i += 256)
            lbase[i] = hist[i] ? (i * CAP + atomicAdd(&gcnt[i * 32], hist[i])) : 0;
        __syncthreads();
#pragma unroll
        for (int i = 0; i < 16; i++) {
            if (se[i] >= 0) {
                const int b = de[i] >> 8;
                const int idx = lbase[b] + mo[i];
                if (idx < (b + 1) * CAP)               // 11-sigma guard
                    tmp[idx] = se[i] | ((de[i] & 255) << 17);
            }
        }
        return;
    }

    // ---- gemm path: xw1 = x @ W1 (bf16 MFMA), fused al1 epilogue ----
    const int rowBase = (blockIdx.x - NPB) * 32;       // 3125 * 32 == 100000
    const int r = t >> 3, j = t & 7;
    const float* xr = x + (long)(rowBase + r) * IN_CH;
    short* xrow = xs + r * 520;
#pragma unroll
    for (int i = 0; i < 16; i++) {
        const int c = j + i * 8;                       // float4 index, 125 per row
        if (c < 125) {
            const float4 v = *(const float4*)(xr + c * 4);
            const unsigned lo = pkbf(v.x, v.y);
            const unsigned hi = pkbf(v.z, v.w);
            *(uint2*)(xrow + c * 4) = make_uint2(lo, hi);
        }
    }
    if (j < 6) *(unsigned*)(xrow + 500 + j * 2) = 0u;  // zero halfs 500..511
    __syncthreads();

    const int lane = t & 63, wv = t >> 6;
    const int m = lane & 15, kg = lane >> 4;
    f32x4 acc[2];
    acc[0] = (f32x4){0.f, 0.f, 0.f, 0.f};
    acc[1] = (f32x4){0.f, 0.f, 0.f, 0.f};
    const short* wcol = wT + (wv * 16 + m) * KPAD;
#pragma unroll
    for (int k0 = 0; k0 < KPAD; k0 += 32) {
        const short8 bf = *(const short8*)(wcol + k0 + kg * 8);
#pragma unroll
        for (int mf = 0; mf < 2; mf++) {
            const short8 af = *(const short8*)(xs + (mf * 16 + m) * 520 + k0 + kg * 8);
            acc[mf] = __builtin_amdgcn_mfma_f32_16x16x32_bf16(af, bf, acc[mf], 0, 0, 0);
        }
    }
    const int col = wv * 16 + m;
    const float as = a1s[col];
    const float ad = a1d[col];
    const int hh = wv * 2 + (m >> 3);
#pragma unroll
    for (int mf = 0; mf < 2; mf++) {
#pragma unroll
        for (int jj = 0; jj < 4; jj++) {
            const int row = rowBase + mf * 16 + kg * 4 + jj;
            const float v = acc[mf][jj];
            xw1b[(long)row * D1 + col] = f2bf(v);
            float ts = v * as, td = v * ad;
            ts += __shfl_xor(ts, 1, 64); td += __shfl_xor(td, 1, 64);
            ts += __shfl_xor(ts, 2, 64); td += __shfl_xor(td, 2, 64);
            ts += __shfl_xor(ts, 4, 64); td += __shfl_xor(td, 4, 64);
            if ((m & 7) == 0) {
                al1s[row * 8 + hh] = ts;
                al1d[row * 8 + hh] = td;
            }
        }
    }
}

// ============ K2: per-bucket CSR build (offsets + scatter), 512 threads ============
__global__ __launch_bounds__(512) void k_bucket2(const int* __restrict__ gcnt,
                                                 const int* __restrict__ tmp,
                                                 int* __restrict__ off,
                                                 int* __restrict__ srt) {
    __shared__ int se[CAP];          // 20 KB bucket edge cache
    __shared__ int cnts[256];
    __shared__ int sc[256];
    __shared__ int lcur[256];
    __shared__ int red[8];
    __shared__ int sbase;
    const int b = blockIdx.x;
    const int t = threadIdx.x;
    const int cnt = min(gcnt[b * 32], CAP);

    int pre = (t < b) ? min(gcnt[t * 32], CAP) : 0;    // 512 threads cover all 391 buckets
#pragma unroll
    for (int m = 1; m < 64; m <<= 1) pre += __shfl_xor(pre, m, 64);
    if ((t & 63) == 0) red[t >> 6] = pre;
    if (t < 256) cnts[t] = 0;
    __syncthreads();
    if (t == 0) {
        int sb = 0;
#pragma unroll
        for (int i = 0; i < 8; i++) sb += red[i];
        sbase = sb;
    }
    __syncthreads();
    const int base = sbase;

    for (int i = t; i < cnt; i += 512) {
        const int p = tmp[b * CAP + i];
        se[i] = p;
        atomicAdd(&cnts[p >> 17], 1);
    }
    __syncthreads();
    if (t < 256) sc[t] = cnts[t];
    __syncthreads();
    for (int d = 1; d < 256; d <<= 1) {
        const int u = (t >= d && t < 256) ? sc[t - d] : 0;
        __syncthreads();
        if (t < 256) sc[t] += u;
        __syncthreads();
    }
    const int nodeBase = b << 8;
    const int nNodes = min(256, N_NODESC - nodeBase);
    if (t < 256) {
        const int excl = base + sc[t] - cnts[t];
        if (t < nNodes) off[nodeBase + t] = excl;
        lcur[t] = excl;
    }
    if (b == 0 && t == 0) off[N_NODESC] = E_TOT;
    __syncthreads();
    for (int i = t; i < cnt; i += 512) {
        const int p = se[i];
        const int pos = atomicAdd(&lcur[p >> 17], 1);
        srt[pos] = p & 0x1FFFF;
    }
}

// ============ K3: gather layer 1, ONE NODE PER BLOCK (32 edge slots x 8 heads) ============
// Single-shot for deg<=32 (99.98% of nodes): no loop-carried dependent chain.
// Wave-level shfl reduce + LDS cross-wave combine; wave 0 does ELU + W2 projection.
__global__ __launch_bounds__(256) void k_gat1(const int* __restrict__ off,
                                              const int* __restrict__ srt_src,
                                              const float* __restrict__ al1s,
                                              const float* __restrict__ al1d,
                                              const short* __restrict__ xw1b,
                                              const float* __restrict__ b1,
                                              const float* __restrict__ W2,
                                              const float* __restrict__ a2s,
                                              const float* __restrict__ a2d,
                                              __half* __restrict__ xw2h,
                                              float* __restrict__ al2d) {
    __shared__ float w2s[D1 * D2];       // 6 KB
    __shared__ float part[3][8][10];     // waves 1..3 partials (9 vals, pad 10)
    __shared__ float hrow[D1];
    const int t = threadIdx.x;
    for (int i = t; i < D1 * D2; i += 256) w2s[i] = W2[i];

    const int n = blockIdx.x;
    const int lane = t & 63, w = t >> 6;
    const int slot = t >> 3;             // 0..31 edge slots
    const int hd = t & 7;                // head / dim-octet

    const float ald = al1d[n * 8 + hd];
    const int kend = off[n + 1];

    float4 a0 = make_float4(0.f, 0.f, 0.f, 0.f);
    float4 a1 = make_float4(0.f, 0.f, 0.f, 0.f);
    float ssum = 0.f;
    for (int k = off[n] + slot; k < kend; k += 32) {   // single trip for deg<=32
        const int s = srt_src[k];
        const float al = al1s[s * 8 + hd];
        const uint4 v = *(const uint4*)(xw1b + (long)s * D1 + hd * 8);
        float ev = al + ald;
        ev = ev > 0.f ? ev : 0.2f * ev;
        const float ex = __expf(ev);
        a0.x += ex * bflo(v.x); a0.y += ex * bfhi(v.x);
        a0.z += ex * bflo(v.y); a0.w += ex * bfhi(v.y);
        a1.x += ex * bflo(v.z); a1.y += ex * bfhi(v.z);
        a1.z += ex * bflo(v.w); a1.w += ex * bfhi(v.w);
        ssum += ex;
    }
    // intra-wave reduce over the wave's 8 edge slots (lane bits 3,4,5)
#pragma unroll
    for (int mm = 8; mm < 64; mm <<= 1) {
        a0.x += __shfl_xor(a0.x, mm, 64); a0.y += __shfl_xor(a0.y, mm, 64);
        a0.z += __shfl_xor(a0.z, mm, 64); a0.w += __shfl_xor(a0.w, mm, 64);
        a1.x += __shfl_xor(a1.x, mm, 64); a1.y += __shfl_xor(a1.y, mm, 64);
        a1.z += __shfl_xor(a1.z, mm, 64); a1.w += __shfl_xor(a1.w, mm, 64);
        ssum  += __shfl_xor(ssum,  mm, 64);
    }
    if (w > 0 && lane < 8) {             // waves 1..3 park partials in LDS
        float* p = &part[w - 1][lane][0];
        p[0] = a0.x; p[1] = a0.y; p[2] = a0.z; p[3] = a0.w;
        p[4] = a1.x; p[5] = a1.y; p[6] = a1.z; p[7] = a1.w;
        p[8] = ssum;
    }
    __syncthreads();
    if (w == 0) {
        float p9[9];
        if (lane < 8) {                  // own partial stays in regs
            p9[0] = a0.x; p9[1] = a0.y; p9[2] = a0.z; p9[3] = a0.w;
            p9[4] = a1.x; p9[5] = a1.y; p9[6] = a1.z; p9[7] = a1.w;
            p9[8] = ssum;
        } else if (lane < 32) {
            const float* p = &part[(lane >> 3) - 1][lane & 7][0];
#pragma unroll
            for (int j = 0; j < 9; j++) p9[j] = p[j];
        } else {
#pragma unroll
            for (int j = 0; j < 9; j++) p9[j] = 0.f;
        }
#pragma unroll
        for (int mm = 8; mm < 32; mm <<= 1)
#pragma unroll
            for (int j = 0; j < 9; j++) p9[j] += __shfl_xor(p9[j], mm, 64);
        if (lane < 8) {                  // lanes 0..7: final per-head-octet totals
            const float inv = 1.0f / (p9[8] + 1e-16f);
            const float4 bb0 = *(const float4*)(b1 + lane * 8);
            const float4 bb1 = *(const float4*)(b1 + lane * 8 + 4);
            float r[8];
            r[0] = p9[0] * inv + bb0.x; r[1] = p9[1] * inv + bb0.y;
            r[2] = p9[2] * inv + bb0.z; r[3] = p9[3] * inv + bb0.w;
            r[4] = p9[4] * inv + bb1.x; r[5] = p9[5] * inv + bb1.y;
            r[6] = p9[6] * inv + bb1.z; r[7] = p9[7] * inv + bb1.w;
#pragma unroll
            for (int i = 0; i < 8; i++) {
                r[i] = r[i] > 0.f ? r[i] : expm1f(r[i]);
                hrow[lane * 8 + i] = r[i];
            }
        }
        // same-wave LDS handoff; W2 projection (c split over two 24-lane halves)
        const int half_ = lane / 24;         // 0,1,2 (lanes 48-63 duplicate half 0)
        const int j2 = lane - half_ * 24;    // 0..23
        const int cb = (half_ == 1) ? 32 : 0;
        float o = 0.f;
#pragma unroll
        for (int c4 = 0; c4 < 8; c4++) {
            const float4 hv = *(const float4*)(&hrow[cb + c4 * 4]);
            const float* wr = w2s + (cb + c4 * 4) * D2 + j2;
            o += hv.x * wr[0] + hv.y * wr[D2] + hv.z * wr[2 * D2] + hv.w * wr[3 * D2];
        }
        const int src2 = (lane < 24) ? lane + 24 : lane;
        o += __shfl(o, src2, 64);            // lanes<24 hold the full 64-dot
        if (lane < 24) {                     // fp16 head-padded row: [8][4]
            const int h3 = j2 / 3;
            xw2h[(long)n * D2P + h3 * 4 + (j2 - 3 * h3)] = __float2half(o);
        }
        const float ps = o * a2s[j2];
        const float pd = o * a2d[j2];
        const int hb = 3 * (lane & 7);
        const float s3 = __shfl(ps, hb, 64) + __shfl(ps, hb + 1, 64) + __shfl(ps, hb + 2, 64);
        const float d3 = __shfl(pd, hb, 64) + __shfl(pd, hb + 1, 64) + __shfl(pd, hb + 2, 64);
        if (lane < 8) {
            xw2h[(long)n * D2P + lane * 4 + 3] = __float2half(s3);  // src-logit in pad slot
            al2d[n * 8 + lane] = d3;
        }
    }
}

// ============ K4: gather layer 2, ONE NODE PER BLOCK + head-mean + softmax ============
// Per edge-lane: ONE 8B fp16 load (head's 3 classes + src logit); 64B line per edge.
__global__ __launch_bounds__(256) void k_gat2(const int* __restrict__ off,
                                              const int* __restrict__ srt_src,
                                              const float* __restrict__ al2d,
                                              const __half* __restrict__ xw2h,
                                              const float* __restrict__ b2,
                                              float* __restrict__ out) {
    __shared__ float part[3][8][5];      // waves 1..3 partials (4 vals, pad 5)
    const int t = threadIdx.x;
    const int n = blockIdx.x;
    const int lane = t & 63, w = t >> 6;
    const int slot = t >> 3;
    const int hd = t & 7;

    const float ald = al2d[n * 8 + hd];
    const int kend = off[n + 1];

    float ax = 0.f, ay = 0.f, az = 0.f, ssum = 0.f;
    for (int k = off[n] + slot; k < kend; k += 32) {
        const int s = srt_src[k];
        const __half2* hp = (const __half2*)(xw2h + (long)s * D2P + hd * 4);
        const float2 f0 = __half22float2(hp[0]);   // c0, c1
        const float2 f1 = __half22float2(hp[1]);   // c2, src-logit
        float ev = f1.y + ald;
        ev = ev > 0.f ? ev : 0.2f * ev;
        const float ex = __expf(ev);
        ax += ex * f0.x; ay += ex * f0.y; az += ex * f1.x;
        ssum += ex;
    }
#pragma unroll
    for (int mm = 8; mm < 64; mm <<= 1) {
        ax += __shfl_xor(ax, mm, 64);
        ay += __shfl_xor(ay, mm, 64);
        az += __shfl_xor(az, mm, 64);
        ssum += __shfl_xor(ssum, mm, 64);
    }
    if (w > 0 && lane < 8) {
        float* p = &part[w - 1][lane][0];
        p[0] = ax; p[1] = ay; p[2] = az; p[3] = ssum;
    }
    __syncthreads();
    if (w == 0) {
        float p4[4];
        if (lane < 8) { p4[0] = ax; p4[1] = ay; p4[2] = az; p4[3] = ssum; }
        else if (lane < 32) {
            const float* p = &part[(lane >> 3) - 1][lane & 7][0];
#pragma unroll
            for (int j = 0; j < 4; j++) p4[j] = p[j];
        } else {
#pragma unroll
            for (int j = 0; j < 4; j++) p4[j] = 0.f;
        }
#pragma unroll
        for (int mm = 8; mm < 32; mm <<= 1)
#pragma unroll
            for (int j = 0; j < 4; j++) p4[j] += __shfl_xor(p4[j], mm, 64);
        // lanes 0..7: per-head alpha-means; then mean over heads (bits 0,1,2)
        const float inv = 1.0f / (p4[3] + 1e-16f);
        float mx = p4[0] * inv, my = p4[1] * inv, mz = p4[2] * inv;
#pragma unroll
        for (int mm = 1; mm < 8; mm <<= 1) {
            mx += __shfl_xor(mx, mm, 64);
            my += __shfl_xor(my, mm, 64);
            mz += __shfl_xor(mz, mm, 64);
        }
        const float l0 = mx * 0.125f + b2[0];
        const float l1 = my * 0.125f + b2[1];
        const float l2 = mz * 0.125f + b2[2];
        const float mmax = fmaxf(l0, fmaxf(l1, l2));
        const float ee0 = expf(l0 - mmax), ee1 = expf(l1 - mmax), ee2 = expf(l2 - mmax);
        const float dinv = 1.0f / (ee0 + ee1 + ee2);
        if (lane < 3) {
            const float p = (lane == 0) ? ee0 : (lane == 1) ? ee1 : ee2;
            out[(long)n * 3 + lane] = p * dinv;
        }
    }
}

extern "C" void kernel_launch(void* const* d_in, const int* in_sizes, int n_in,
                              void* d_out, int out_size, void* d_ws, size_t ws_size,
                              hipStream_t stream) {
    const float* x   = (const float*)d_in[0];
    const float* W1  = (const float*)d_in[1];
    const float* a1s = (const float*)d_in[2];
    const float* a1d = (const float*)d_in[3];
    const float* b1  = (const float*)d_in[4];
    const float* W2  = (const float*)d_in[5];
    const float* a2s = (const float*)d_in[6];
    const float* a2d = (const float*)d_in[7];
    const float* b2  = (const float*)d_in[8];
    const int*   ei  = (const int*)d_in[9];
    float* out = (float*)d_out;

    float* ws    = (float*)d_ws;
    float* al1s  = ws;                        //   800,000
    float* al1d  = al1s + 800000;             //   800,000
    float* al2d  = al1d + 800000;             //   800,000
    short* xw1b  = (short*)(al2d + 800000);   // 6,400,000 shorts (bf16)
    __half* xw2h = (__half*)(xw1b + 6400000); // 3,200,000 halfs (fp16)
    int* off     = (int*)(xw2h + 3200000);    //   100,004
    int* gcnt    = off + 100004;              //   391*32 line-padded cursors
    int* srt     = gcnt + NBKT * 32;          // 1,700,000
    short* wT    = (short*)(srt + 1700000);   //   64*512 halfs (16B aligned)
    int* tmp     = (int*)(wT + 32768);        //   391*5120 = 2,001,920 ints

    k_init<<<64, 256, 0, stream>>>(gcnt, W1, wT);
    k_pg<<<NPB + GEMB, 256, 0, stream>>>(ei, gcnt, tmp, x, wT, a1s, a1d,
                                         xw1b, al1s, al1d);
    k_bucket2<<<NBKT, 512, 0, stream>>>(gcnt, tmp, off, srt);
    k_gat1<<<N_NODESC, 256, 0, stream>>>(off, srt, al1s, al1d, xw1b, b1,
                                         W2, a2s, a2d, xw2h, al2d);
    k_gat2<<<N_NODESC, 256, 0, stream>>>(off, srt, al2d, xw2h, b2, out);
}

// Round 7
// 469.046 us; speedup vs baseline: 1.3435x; 1.3435x over previous
//
#include <hip/hip_runtime.h>
#include <hip/hip_fp16.h>
#include <math.h>

#define N_NODESC 100000
#define N_EDGESC 1600000
#define E_TOT    1700000   // incl. self loops
#define IN_CH    500
#define KPAD     512
#define D1 64
#define D2 24
#define D2P 32             // xw2 row: 8 heads x (3 classes + src-logit), fp16 = 64B
#define NBKT 391           // dst buckets of 256 nodes
#define CAP  5120          // fixed bucket capacity (mean 4352, sigma ~66 -> 11 sigma)
#define EPB  4096          // edges per partition block
#define NPB  416           // ceil(E_TOT/EPB) partition blocks
#define GEMB 3125          // gemm blocks (100000/32)

typedef __attribute__((ext_vector_type(8))) short short8;
typedef __attribute__((ext_vector_type(4))) float f32x4;

__device__ inline short f2bf(float f) {            // RTNE fp32 -> bf16
    unsigned u = __float_as_uint(f);
    u += 0x7fffu + ((u >> 16) & 1u);
    return (short)(u >> 16);
}
__device__ inline unsigned pkbf(float a, float b) {
    const unsigned ua = __float_as_uint(a) + 0x8000u;
    const unsigned ub = __float_as_uint(b) + 0x8000u;
    return __builtin_amdgcn_perm(ub, ua, 0x07060302u);  // lo16=a_bf, hi16=b_bf
}
__device__ inline float bflo(unsigned u) { return __uint_as_float(u << 16); }
__device__ inline float bfhi(unsigned u) { return __uint_as_float(u & 0xffff0000u); }

// ============ K0: zero bucket cursors + W1 -> bf16 transposed ============
__global__ __launch_bounds__(256) void k_init(int* __restrict__ gcnt,
                                              const float* __restrict__ W1,
                                              short* __restrict__ wT) {
    const int tid = blockIdx.x * 256 + threadIdx.x;     // 64 blocks -> 16384 threads
    for (int i = tid; i < D1 * KPAD; i += 16384) {
        const int n = i >> 9, k = i & (KPAD - 1);
        wT[i] = (k < IN_CH) ? f2bf(W1[k * D1 + n]) : (short)0;
    }
    for (int i = tid; i < NBKT * 32; i += 16384) gcnt[i] = 0;
}

// ============ K1 (fused): edge partition [0..NPB) + gemm1 [NPB..) ============
__global__ __launch_bounds__(256) void k_pg(const int* __restrict__ ei,
                                            int* __restrict__ gcnt,   // stride 32
                                            int* __restrict__ tmp,
                                            const float* __restrict__ x,
                                            const short* __restrict__ wT,
                                            const float* __restrict__ a1s,
                                            const float* __restrict__ a1d,
                                            short* __restrict__ xw1b,
                                            float* __restrict__ al1s,
                                            float* __restrict__ al1d) {
    __shared__ short xs[32 * 520];                     // 33.3 KB; partition path aliases it
    const int t = threadIdx.x;

    if (blockIdx.x < NPB) {                            // ---- partition path ----
        int* hist  = (int*)xs;                         // NBKT ints
        int* lbase = hist + NBKT;                      // NBKT ints
        const int e0 = blockIdx.x * EPB;
        for (int i = t; i < NBKT; i += 256) hist[i] = 0;
        __syncthreads();
        int se[16], de[16], mo[16];
#pragma unroll
        for (int i = 0; i < 16; i++) {
            const int e = e0 + i * 256 + t;
            int s = -1, d = 0;
            if (e < E_TOT) {
                if (e < N_EDGESC) { s = ei[e]; d = ei[N_EDGESC + e]; }
                else { s = d = e - N_EDGESC; }
            }
            se[i] = s; de[i] = d;
            mo[i] = (s >= 0) ? atomicAdd(&hist[d >> 8], 1) : 0;
        }
        __syncthreads();
        for (int i = t; i < NBKT; i += 256)
            lbase[i] = hist[i] ? (i * CAP + atomicAdd(&gcnt[i * 32], hist[i])) : 0;
        __syncthreads();
#pragma unroll
        for (int i = 0; i < 16; i++) {
            if (se[i] >= 0) {
                const int b = de[i] >> 8;
                const int idx = lbase[b] + mo[i];
                if (idx < (b + 1) * CAP)               // 11-sigma guard
                    tmp[idx] = se[i] | ((de[i] & 255) << 17);
            }
        }
        return;
    }

    // ---- gemm path: xw1 = x @ W1 (bf16 MFMA), fused al1 epilogue ----
    const int rowBase = (blockIdx.x - NPB) * 32;       // 3125 * 32 == 100000
    const int r = t >> 3, j = t & 7;
    const float* xr = x + (long)(rowBase + r) * IN_CH;
    short* xrow = xs + r * 520;
#pragma unroll
    for (int i = 0; i < 16; i++) {
        const int c = j + i * 8;                       // float4 index, 125 per row
        if (c < 125) {
            const float4 v = *(const float4*)(xr + c * 4);
            const unsigned lo = pkbf(v.x, v.y);
            const unsigned hi = pkbf(v.z, v.w);
            *(uint2*)(xrow + c * 4) = make_uint2(lo, hi);
        }
    }
    if (j < 6) *(unsigned*)(xrow + 500 + j * 2) = 0u;  // zero halfs 500..511
    __syncthreads();

    const int lane = t & 63, wv = t >> 6;
    const int m = lane & 15, kg = lane >> 4;
    f32x4 acc[2];
    acc[0] = (f32x4){0.f, 0.f, 0.f, 0.f};
    acc[1] = (f32x4){0.f, 0.f, 0.f, 0.f};
    const short* wcol = wT + (wv * 16 + m) * KPAD;
#pragma unroll
    for (int k0 = 0; k0 < KPAD; k0 += 32) {
        const short8 bf = *(const short8*)(wcol + k0 + kg * 8);
#pragma unroll
        for (int mf = 0; mf < 2; mf++) {
            const short8 af = *(const short8*)(xs + (mf * 16 + m) * 520 + k0 + kg * 8);
            acc[mf] = __builtin_amdgcn_mfma_f32_16x16x32_bf16(af, bf, acc[mf], 0, 0, 0);
        }
    }
    const int col = wv * 16 + m;
    const float as = a1s[col];
    const float ad = a1d[col];
    const int hh = wv * 2 + (m >> 3);
#pragma unroll
    for (int mf = 0; mf < 2; mf++) {
#pragma unroll
        for (int jj = 0; jj < 4; jj++) {
            const int row = rowBase + mf * 16 + kg * 4 + jj;
            const float v = acc[mf][jj];
            xw1b[(long)row * D1 + col] = f2bf(v);
            float ts = v * as, td = v * ad;
            ts += __shfl_xor(ts, 1, 64); td += __shfl_xor(td, 1, 64);
            ts += __shfl_xor(ts, 2, 64); td += __shfl_xor(td, 2, 64);
            ts += __shfl_xor(ts, 4, 64); td += __shfl_xor(td, 4, 64);
            if ((m & 7) == 0) {
                al1s[row * 8 + hh] = ts;
                al1d[row * 8 + hh] = td;
            }
        }
    }
}

// ============ K2: per-bucket CSR build (offsets + scatter), 512 threads ============
__global__ __launch_bounds__(512) void k_bucket2(const int* __restrict__ gcnt,
                                                 const int* __restrict__ tmp,
                                                 int* __restrict__ off,
                                                 int* __restrict__ srt) {
    __shared__ int se[CAP];          // 20 KB bucket edge cache
    __shared__ int cnts[256];
    __shared__ int sc[256];
    __shared__ int lcur[256];
    __shared__ int red[8];
    __shared__ int sbase;
    const int b = blockIdx.x;
    const int t = threadIdx.x;
    const int cnt = min(gcnt[b * 32], CAP);

    int pre = (t < b) ? min(gcnt[t * 32], CAP) : 0;    // 512 threads cover all 391 buckets
#pragma unroll
    for (int m = 1; m < 64; m <<= 1) pre += __shfl_xor(pre, m, 64);
    if ((t & 63) == 0) red[t >> 6] = pre;
    if (t < 256) cnts[t] = 0;
    __syncthreads();
    if (t == 0) {
        int sb = 0;
#pragma unroll
        for (int i = 0; i < 8; i++) sb += red[i];
        sbase = sb;
    }
    __syncthreads();
    const int base = sbase;

    for (int i = t; i < cnt; i += 512) {
        const int p = tmp[b * CAP + i];
        se[i] = p;
        atomicAdd(&cnts[p >> 17], 1);
    }
    __syncthreads();
    if (t < 256) sc[t] = cnts[t];
    __syncthreads();
    for (int d = 1; d < 256; d <<= 1) {
        const int u = (t >= d && t < 256) ? sc[t - d] : 0;
        __syncthreads();
        if (t < 256) sc[t] += u;
        __syncthreads();
    }
    const int nodeBase = b << 8;
    const int nNodes = min(256, N_NODESC - nodeBase);
    if (t < 256) {
        const int excl = base + sc[t] - cnts[t];
        if (t < nNodes) off[nodeBase + t] = excl;
        lcur[t] = excl;
    }
    if (b == 0 && t == 0) off[N_NODESC] = E_TOT;
    __syncthreads();
    for (int i = t; i < cnt; i += 512) {
        const int p = se[i];
        const int pos = atomicAdd(&lcur[p >> 17], 1);
        srt[pos] = p & 0x1FFFF;
    }
}

// ============ K3: gather-aggregate layer 1 + fused layer-2 projection ============
// 4 nodes/block, wave-per-node, lane = (edge-slot e8, head hd). Software-pipelined.
// W2 LDS staging latency hidden under the edge gather (barrier moved after loop).
__global__ __launch_bounds__(256) void k_gat1(const int* __restrict__ off,
                                              const int* __restrict__ srt_src,
                                              const float* __restrict__ al1s,
                                              const float* __restrict__ al1d,
                                              const short* __restrict__ xw1b,
                                              const float* __restrict__ b1,
                                              const float* __restrict__ W2,
                                              const float* __restrict__ a2s,
                                              const float* __restrict__ a2d,
                                              __half* __restrict__ xw2h,
                                              float* __restrict__ al2d) {
    __shared__ float w2s[D1 * D2];
    __shared__ float hrow[4][D1];
    const int tid = threadIdx.x;
    for (int i = tid; i < D1 * D2; i += 256) w2s[i] = W2[i];   // no barrier yet

    const int lane = tid & 63;
    const int wid = tid >> 6;
    const int n = blockIdx.x * 4 + wid;   // N_NODESC % 4 == 0
    const int e8 = lane >> 3;             // edge slot 0..7
    const int hd = lane & 7;              // head 0..7 (= dim octet)

    const float ald = al1d[n * 8 + hd];
    const int kend = off[n + 1];

    float4 a0 = make_float4(0.f, 0.f, 0.f, 0.f);
    float4 a1 = make_float4(0.f, 0.f, 0.f, 0.f);
    float ssum = 0.f;
    int k = off[n] + e8;
    int s = (k < kend) ? srt_src[k] : -1;
    float al = 0.f;
    uint4 v = make_uint4(0u, 0u, 0u, 0u);
    if (s >= 0) {
        al = al1s[s * 8 + hd];
        v = *(const uint4*)(xw1b + (long)s * D1 + hd * 8);
    }
    while (s >= 0) {
        const int kn = k + 8;
        const int sn = (kn < kend) ? srt_src[kn] : -1;
        float aln = 0.f;
        uint4 vn = v;
        if (sn >= 0) {                               // prefetch next edge's data
            aln = al1s[sn * 8 + hd];
            vn = *(const uint4*)(xw1b + (long)sn * D1 + hd * 8);
        }
        float ev = al + ald;
        ev = ev > 0.f ? ev : 0.2f * ev;
        const float ex = __expf(ev);
        a0.x += ex * bflo(v.x); a0.y += ex * bfhi(v.x);
        a0.z += ex * bflo(v.y); a0.w += ex * bfhi(v.y);
        a1.x += ex * bflo(v.z); a1.y += ex * bfhi(v.z);
        a1.z += ex * bflo(v.w); a1.w += ex * bfhi(v.w);
        ssum += ex;
        k = kn; s = sn; al = aln; v = vn;
    }
    // reduce across the 8 edge slots (lane bits 3,4,5)
#pragma unroll
    for (int mm = 8; mm < 64; mm <<= 1) {
        a0.x += __shfl_xor(a0.x, mm, 64); a0.y += __shfl_xor(a0.y, mm, 64);
        a0.z += __shfl_xor(a0.z, mm, 64); a0.w += __shfl_xor(a0.w, mm, 64);
        a1.x += __shfl_xor(a1.x, mm, 64); a1.y += __shfl_xor(a1.y, mm, 64);
        a1.z += __shfl_xor(a1.z, mm, 64); a1.w += __shfl_xor(a1.w, mm, 64);
        ssum  += __shfl_xor(ssum,  mm, 64);
    }
    const float inv = 1.0f / (ssum + 1e-16f);
    const float4 bb0 = *(const float4*)(b1 + hd * 8);
    const float4 bb1 = *(const float4*)(b1 + hd * 8 + 4);
    float4 r0, r1;
    r0.x = a0.x * inv + bb0.x; r0.x = r0.x > 0.f ? r0.x : expm1f(r0.x);
    r0.y = a0.y * inv + bb0.y; r0.y = r0.y > 0.f ? r0.y : expm1f(r0.y);
    r0.z = a0.z * inv + bb0.z; r0.z = r0.z > 0.f ? r0.z : expm1f(r0.z);
    r0.w = a0.w * inv + bb0.w; r0.w = r0.w > 0.f ? r0.w : expm1f(r0.w);
    r1.x = a1.x * inv + bb1.x; r1.x = r1.x > 0.f ? r1.x : expm1f(r1.x);
    r1.y = a1.y * inv + bb1.y; r1.y = r1.y > 0.f ? r1.y : expm1f(r1.y);
    r1.z = a1.z * inv + bb1.z; r1.z = r1.z > 0.f ? r1.z : expm1f(r1.z);
    r1.w = a1.w * inv + bb1.w; r1.w = r1.w > 0.f ? r1.w : expm1f(r1.w);
    if (e8 == 0) {                          // lanes 0..7: write dims hd*8..hd*8+7
        *(float4*)(&hrow[wid][hd * 8])     = r0;
        *(float4*)(&hrow[wid][hd * 8 + 4]) = r1;
    }
    __syncthreads();                        // w2s fill -> first w2s read
    // layer-2 projection: c split over two 24-lane half-groups
    const int half_ = lane / 24;             // 0,1,2 (lanes 48-63 duplicate half 0)
    const int j2 = lane - half_ * 24;        // 0..23
    const int cb = (half_ == 1) ? 32 : 0;
    float o = 0.f;
#pragma unroll
    for (int c4 = 0; c4 < 8; c4++) {
        const float4 hv = *(const float4*)(&hrow[wid][cb + c4 * 4]);  // broadcast read
        const float* wr = w2s + (cb + c4 * 4) * D2 + j2;
        o += hv.x * wr[0] + hv.y * wr[D2] + hv.z * wr[2 * D2] + hv.w * wr[3 * D2];
    }
    const int src2 = (lane < 24) ? lane + 24 : lane;
    o += __shfl(o, src2, 64);                // lanes<24 hold the full 64-dot
    if (lane < 24) {                         // fp16 head-padded row: [8][4]
        const int h3 = j2 / 3;
        xw2h[(long)n * D2P + h3 * 4 + (j2 - 3 * h3)] = __float2half(o);
    }
    const float ps = o * a2s[j2];
    const float pd = o * a2d[j2];
    const int hb = 3 * (lane & 7);
    const float s3 = __shfl(ps, hb, 64) + __shfl(ps, hb + 1, 64) + __shfl(ps, hb + 2, 64);
    const float d3 = __shfl(pd, hb, 64) + __shfl(pd, hb + 1, 64) + __shfl(pd, hb + 2, 64);
    if (lane < 8) {
        xw2h[(long)n * D2P + lane * 4 + 3] = __float2half(s3);  // src-logit in pad slot
        al2d[n * 8 + lane] = d3;
    }
}

// ============ K4: gather-aggregate layer 2 + head-mean + softmax ============
// 4 nodes/block, wave-per-node. ONE 8B fp16 load per edge-lane (classes + logit):
// one 64B line per edge. Software-pipelined.
__global__ __launch_bounds__(256) void k_gat2(const int* __restrict__ off,
                                              const int* __restrict__ srt_src,
                                              const float* __restrict__ al2d,
                                              const __half* __restrict__ xw2h,
                                              const float* __restrict__ b2,
                                              float* __restrict__ out) {
    const int tid = threadIdx.x;
    const int lane = tid & 63;
    const int wid = tid >> 6;
    const int n = blockIdx.x * 4 + wid;
    const int e8 = lane >> 3;
    const int hd = lane & 7;

    const float ald = al2d[n * 8 + hd];
    const int kend = off[n + 1];

    float ax = 0.f, ay = 0.f, az = 0.f, ssum = 0.f;
    int k = off[n] + e8;
    int s = (k < kend) ? srt_src[k] : -1;
    uint2 v = make_uint2(0u, 0u);
    if (s >= 0) v = *(const uint2*)(xw2h + (long)s * D2P + hd * 4);
    while (s >= 0) {
        const int kn = k + 8;
        const int sn = (kn < kend) ? srt_src[kn] : -1;
        uint2 vn = v;
        if (sn >= 0) vn = *(const uint2*)(xw2h + (long)sn * D2P + hd * 4);
        const float2 f0 = __half22float2(*(const __half2*)&v.x);   // c0, c1
        const float2 f1 = __half22float2(*(const __half2*)&v.y);   // c2, src-logit
        float ev = f1.y + ald;
        ev = ev > 0.f ? ev : 0.2f * ev;
        const float ex = __expf(ev);
        ax += ex * f0.x; ay += ex * f0.y; az += ex * f1.x;
        ssum += ex;
        k = kn; s = sn; v = vn;
    }
    // reduce across 8 edge slots (bits 3,4,5)
#pragma unroll
    for (int mm = 8; mm < 64; mm <<= 1) {
        ax += __shfl_xor(ax, mm, 64);
        ay += __shfl_xor(ay, mm, 64);
        az += __shfl_xor(az, mm, 64);
        ssum += __shfl_xor(ssum, mm, 64);
    }
    const float inv = 1.0f / (ssum + 1e-16f);
    float mx = ax * inv, my = ay * inv, mz = az * inv;   // this head's alpha-mean
    // head mean: reduce over head bits 0,1,2
#pragma unroll
    for (int mm = 1; mm < 8; mm <<= 1) {
        mx += __shfl_xor(mx, mm, 64);
        my += __shfl_xor(my, mm, 64);
        mz += __shfl_xor(mz, mm, 64);
    }
    const float l0 = mx * 0.125f + b2[0];
    const float l1 = my * 0.125f + b2[1];
    const float l2 = mz * 0.125f + b2[2];
    const float mmax = fmaxf(l0, fmaxf(l1, l2));
    const float ee0 = expf(l0 - mmax), ee1 = expf(l1 - mmax), ee2 = expf(l2 - mmax);
    const float dinv = 1.0f / (ee0 + ee1 + ee2);
    if (lane < 3) {
        const float p = (lane == 0) ? ee0 : (lane == 1) ? ee1 : ee2;
        out[(long)n * 3 + lane] = p * dinv;
    }
}

extern "C" void kernel_launch(void* const* d_in, const int* in_sizes, int n_in,
                              void* d_out, int out_size, void* d_ws, size_t ws_size,
                              hipStream_t stream) {
    const float* x   = (const float*)d_in[0];
    const float* W1  = (const float*)d_in[1];
    const float* a1s = (const float*)d_in[2];
    const float* a1d = (const float*)d_in[3];
    const float* b1  = (const float*)d_in[4];
    const float* W2  = (const float*)d_in[5];
    const float* a2s = (const float*)d_in[6];
    const float* a2d = (const float*)d_in[7];
    const float* b2  = (const float*)d_in[8];
    const int*   ei  = (const int*)d_in[9];
    float* out = (float*)d_out;

    float* ws    = (float*)d_ws;
    float* al1s  = ws;                        //   800,000
    float* al1d  = al1s + 800000;             //   800,000
    float* al2d  = al1d + 800000;             //   800,000
    short* xw1b  = (short*)(al2d + 800000);   // 6,400,000 shorts (bf16)
    __half* xw2h = (__half*)(xw1b + 6400000); // 3,200,000 halfs (fp16)
    int* off     = (int*)(xw2h + 3200000);    //   100,004
    int* gcnt    = off + 100004;              //   391*32 line-padded cursors
    int* srt     = gcnt + NBKT * 32;          // 1,700,000
    short* wT    = (short*)(srt + 1700000);   //   64*512 halfs (16B aligned)
    int* tmp     = (int*)(wT + 32768);        //   391*5120 = 2,001,920 ints

    k_init<<<64, 256, 0, stream>>>(gcnt, W1, wT);
    k_pg<<<NPB + GEMB, 256, 0, stream>>>(ei, gcnt, tmp, x, wT, a1s, a1d,
                                         xw1b, al1s, al1d);
    k_bucket2<<<NBKT, 512, 0, stream>>>(gcnt, tmp, off, srt);
    k_gat1<<<N_NODESC / 4, 256, 0, stream>>>(off, srt, al1s, al1d, xw1b, b1,
                                             W2, a2s, a2d, xw2h, al2d);
    k_gat2<<<N_NODESC / 4, 256, 0, stream>>>(off, srt, al2d, xw2h, b2, out);
}

// Round 9
// 452.988 us; speedup vs baseline: 1.3912x; 1.0354x over previous
//
#include <hip/hip_runtime.h>
#include <hip/hip_fp16.h>
#include <math.h>

#define N_NODESC 100000
#define N_EDGESC 1600000
#define E_TOT    1700000   // incl. self loops
#define IN_CH    500
#define KPAD     512
#define D1 64
#define D2 24
#define D2P 32             // xw2 row: 8 heads x (3 classes + src-logit), fp16 = 64B
#define NBKT 391           // dst buckets of 256 nodes
#define CAP  5120          // fixed bucket capacity (mean 4352, sigma ~66 -> 11 sigma)
#define EPB  4096          // edges per partition block
#define NPB  416           // ceil(E_TOT/EPB) partition blocks
#define GEMB 3125          // gemm blocks (100000/32)

typedef __attribute__((ext_vector_type(8))) short short8;
typedef __attribute__((ext_vector_type(4))) float f32x4;

__device__ inline short f2bf(float f) {            // RTNE fp32 -> bf16
    unsigned u = __float_as_uint(f);
    u += 0x7fffu + ((u >> 16) & 1u);
    return (short)(u >> 16);
}
__device__ inline unsigned pkbf(float a, float b) {
    const unsigned ua = __float_as_uint(a) + 0x8000u;
    const unsigned ub = __float_as_uint(b) + 0x8000u;
    return __builtin_amdgcn_perm(ub, ua, 0x07060302u);  // lo16=a_bf, hi16=b_bf
}
__device__ inline float bflo(unsigned u) { return __uint_as_float(u << 16); }
__device__ inline float bfhi(unsigned u) { return __uint_as_float(u & 0xffff0000u); }

// ============ K0: zero bucket cursors + W1 -> bf16 transposed ============
__global__ __launch_bounds__(256) void k_init(int* __restrict__ gcnt,
                                              const float* __restrict__ W1,
                                              short* __restrict__ wT) {
    const int tid = blockIdx.x * 256 + threadIdx.x;     // 64 blocks -> 16384 threads
    for (int i = tid; i < D1 * KPAD; i += 16384) {
        const int n = i >> 9, k = i & (KPAD - 1);
        wT[i] = (k < IN_CH) ? f2bf(W1[k * D1 + n]) : (short)0;
    }
    for (int i = tid; i < NBKT * 32; i += 16384) gcnt[i] = 0;
}

// ============ K1 (fused): edge partition [0..NPB) + gemm1 [NPB..) ============
__global__ __launch_bounds__(256) void k_pg(const int* __restrict__ ei,
                                            int* __restrict__ gcnt,   // stride 32
                                            int* __restrict__ tmp,
                                            const float* __restrict__ x,
                                            const short* __restrict__ wT,
                                            const float* __restrict__ a1s,
                                            const float* __restrict__ a1d,
                                            short* __restrict__ xw1b,
                                            float* __restrict__ al1s,
                                            float* __restrict__ al1d) {
    __shared__ short xs[32 * 520];                     // 33.3 KB; partition path aliases it
    const int t = threadIdx.x;

    if (blockIdx.x < NPB) {                            // ---- partition path ----
        int* hist  = (int*)xs;                         // NBKT ints
        int* lbase = hist + NBKT;                      // NBKT ints
        const int e0 = blockIdx.x * EPB;
        for (int i = t; i < NBKT; i += 256) hist[i] = 0;
        __syncthreads();
        int se[16], de[16], mo[16];
#pragma unroll
        for (int i = 0; i < 16; i++) {
            const int e = e0 + i * 256 + t;
            int s = -1, d = 0;
            if (e < E_TOT) {
                if (e < N_EDGESC) { s = ei[e]; d = ei[N_EDGESC + e]; }
                else { s = d = e - N_EDGESC; }
            }
            se[i] = s; de[i] = d;
            mo[i] = (s >= 0) ? atomicAdd(&hist[d >> 8], 1) : 0;
        }
        __syncthreads();
        for (int i = t; i < NBKT; i += 256)
            lbase[i] = hist[i] ? (i * CAP + atomicAdd(&gcnt[i * 32], hist[i])) : 0;
        __syncthreads();
#pragma unroll
        for (int i = 0; i < 16; i++) {
            if (se[i] >= 0) {
                const int b = de[i] >> 8;
                const int idx = lbase[b] + mo[i];
                if (idx < (b + 1) * CAP)               // 11-sigma guard
                    tmp[idx] = se[i] | ((de[i] & 255) << 17);
            }
        }
        return;
    }

    // ---- gemm path: xw1 = x @ W1 (bf16 MFMA), fused al1 epilogue ----
    const int rowBase = (blockIdx.x - NPB) * 32;       // 3125 * 32 == 100000
    const int r = t >> 3, j = t & 7;
    const float* xr = x + (long)(rowBase + r) * IN_CH;
    short* xrow = xs + r * 520;
#pragma unroll
    for (int i = 0; i < 16; i++) {
        const int c = j + i * 8;                       // float4 index, 125 per row
        if (c < 125) {
            const float4 v = *(const float4*)(xr + c * 4);
            const unsigned lo = pkbf(v.x, v.y);
            const unsigned hi = pkbf(v.z, v.w);
            *(uint2*)(xrow + c * 4) = make_uint2(lo, hi);
        }
    }
    if (j < 6) *(unsigned*)(xrow + 500 + j * 2) = 0u;  // zero halfs 500..511
    __syncthreads();

    const int lane = t & 63, wv = t >> 6;
    const int m = lane & 15, kg = lane >> 4;
    f32x4 acc[2];
    acc[0] = (f32x4){0.f, 0.f, 0.f, 0.f};
    acc[1] = (f32x4){0.f, 0.f, 0.f, 0.f};
    const short* wcol = wT + (wv * 16 + m) * KPAD;
#pragma unroll
    for (int k0 = 0; k0 < KPAD; k0 += 32) {
        const short8 bf = *(const short8*)(wcol + k0 + kg * 8);
#pragma unroll
        for (int mf = 0; mf < 2; mf++) {
            const short8 af = *(const short8*)(xs + (mf * 16 + m) * 520 + k0 + kg * 8);
            acc[mf] = __builtin_amdgcn_mfma_f32_16x16x32_bf16(af, bf, acc[mf], 0, 0, 0);
        }
    }
    const int col = wv * 16 + m;
    const float as = a1s[col];
    const float ad = a1d[col];
    const int hh = wv * 2 + (m >> 3);
#pragma unroll
    for (int mf = 0; mf < 2; mf++) {
#pragma unroll
        for (int jj = 0; jj < 4; jj++) {
            const int row = rowBase + mf * 16 + kg * 4 + jj;
            const float v = acc[mf][jj];
            xw1b[(long)row * D1 + col] = f2bf(v);
            float ts = v * as, td = v * ad;
            ts += __shfl_xor(ts, 1, 64); td += __shfl_xor(td, 1, 64);
            ts += __shfl_xor(ts, 2, 64); td += __shfl_xor(td, 2, 64);
            ts += __shfl_xor(ts, 4, 64); td += __shfl_xor(td, 4, 64);
            if ((m & 7) == 0) {
                al1s[row * 8 + hh] = ts;
                al1d[row * 8 + hh] = td;
            }
        }
    }
}

// ============ K2: per-bucket CSR build (offsets + scatter), 512 threads ============
__global__ __launch_bounds__(512) void k_bucket2(const int* __restrict__ gcnt,
                                                 const int* __restrict__ tmp,
                                                 int* __restrict__ off,
                                                 int* __restrict__ srt) {
    __shared__ int se[CAP];          // 20 KB bucket edge cache
    __shared__ int cnts[256];
    __shared__ int sc[256];
    __shared__ int lcur[256];
    __shared__ int red[8];
    __shared__ int sbase;
    const int b = blockIdx.x;
    const int t = threadIdx.x;
    const int cnt = min(gcnt[b * 32], CAP);

    int pre = (t < b) ? min(gcnt[t * 32], CAP) : 0;    // 512 threads cover all 391 buckets
#pragma unroll
    for (int m = 1; m < 64; m <<= 1) pre += __shfl_xor(pre, m, 64);
    if ((t & 63) == 0) red[t >> 6] = pre;
    if (t < 256) cnts[t] = 0;
    __syncthreads();
    if (t == 0) {
        int sb = 0;
#pragma unroll
        for (int i = 0; i < 8; i++) sb += red[i];
        sbase = sb;
    }
    __syncthreads();
    const int base = sbase;

    for (int i = t; i < cnt; i += 512) {
        const int p = tmp[b * CAP + i];
        se[i] = p;
        atomicAdd(&cnts[p >> 17], 1);
    }
    __syncthreads();
    if (t < 256) sc[t] = cnts[t];
    __syncthreads();
    for (int d = 1; d < 256; d <<= 1) {
        const int u = (t >= d && t < 256) ? sc[t - d] : 0;
        __syncthreads();
        if (t < 256) sc[t] += u;
        __syncthreads();
    }
    const int nodeBase = b << 8;
    const int nNodes = min(256, N_NODESC - nodeBase);
    if (t < 256) {
        const int excl = base + sc[t] - cnts[t];
        if (t < nNodes) off[nodeBase + t] = excl;
        lcur[t] = excl;
    }
    if (b == 0 && t == 0) off[N_NODESC] = E_TOT;
    __syncthreads();
    for (int i = t; i < cnt; i += 512) {
        const int p = se[i];
        const int pos = atomicAdd(&lcur[p >> 17], 1);
        srt[pos] = p & 0x1FFFF;
    }
}

// ============ K3: gather layer 1 + fused layer-2 projection ============
// 8 nodes/block (512 thr), wave-per-node, lane = (edge-slot e8, head hd).
// Batch-3 gather: all 3 trips' indices issued together, then all data loads
// concurrently -> dependent-chain depth 1 for deg<=24 (~96% of nodes).
__global__ __launch_bounds__(512) void k_gat1(const int* __restrict__ off,
                                              const int* __restrict__ srt_src,
                                              const float* __restrict__ al1s,
                                              const float* __restrict__ al1d,
                                              const short* __restrict__ xw1b,
                                              const float* __restrict__ b1,
                                              const float* __restrict__ W2,
                                              const float* __restrict__ a2s,
                                              const float* __restrict__ a2d,
                                              __half* __restrict__ xw2h,
                                              float* __restrict__ al2d) {
    __shared__ float w2s[D1 * D2];
    __shared__ float hrow[8][D1];
    const int tid = threadIdx.x;
    for (int i = tid; i < D1 * D2; i += 512) w2s[i] = W2[i];   // barrier deferred

    const int lane = tid & 63;
    const int wid = tid >> 6;
    const int n = blockIdx.x * 8 + wid;   // N_NODESC % 8 == 0
    const int e8 = lane >> 3;             // edge slot 0..7
    const int hd = lane & 7;              // head 0..7 (= dim octet)

    const float ald = al1d[n * 8 + hd];
    const int kbeg = off[n], kend = off[n + 1];

    float4 a0 = make_float4(0.f, 0.f, 0.f, 0.f);
    float4 a1 = make_float4(0.f, 0.f, 0.f, 0.f);
    float ssum = 0.f;
    int k = kbeg + e8;
    // ---- batch of 3: indices first (independent), then all data loads ----
    const int s0 = (k      < kend) ? srt_src[k]      : -1;
    const int s1 = (k + 8  < kend) ? srt_src[k + 8]  : -1;
    const int s2 = (k + 16 < kend) ? srt_src[k + 16] : -1;
    float l0 = 0.f, l1 = 0.f, l2 = 0.f;
    uint4 v0 = make_uint4(0u, 0u, 0u, 0u);
    uint4 v1 = make_uint4(0u, 0u, 0u, 0u);
    uint4 v2 = make_uint4(0u, 0u, 0u, 0u);
    if (s0 >= 0) { l0 = al1s[s0 * 8 + hd]; v0 = *(const uint4*)(xw1b + (long)s0 * D1 + hd * 8); }
    if (s1 >= 0) { l1 = al1s[s1 * 8 + hd]; v1 = *(const uint4*)(xw1b + (long)s1 * D1 + hd * 8); }
    if (s2 >= 0) { l2 = al1s[s2 * 8 + hd]; v2 = *(const uint4*)(xw1b + (long)s2 * D1 + hd * 8); }
    if (s0 >= 0) {
        float ev = l0 + ald; ev = ev > 0.f ? ev : 0.2f * ev;
        const float ex = __expf(ev);
        a0.x += ex * bflo(v0.x); a0.y += ex * bfhi(v0.x);
        a0.z += ex * bflo(v0.y); a0.w += ex * bfhi(v0.y);
        a1.x += ex * bflo(v0.z); a1.y += ex * bfhi(v0.z);
        a1.z += ex * bflo(v0.w); a1.w += ex * bfhi(v0.w);
        ssum += ex;
    }
    if (s1 >= 0) {
        float ev = l1 + ald; ev = ev > 0.f ? ev : 0.2f * ev;
        const float ex = __expf(ev);
        a0.x += ex * bflo(v1.x); a0.y += ex * bfhi(v1.x);
        a0.z += ex * bflo(v1.y); a0.w += ex * bfhi(v1.y);
        a1.x += ex * bflo(v1.z); a1.y += ex * bfhi(v1.z);
        a1.z += ex * bflo(v1.w); a1.w += ex * bfhi(v1.w);
        ssum += ex;
    }
    if (s2 >= 0) {
        float ev = l2 + ald; ev = ev > 0.f ? ev : 0.2f * ev;
        const float ex = __expf(ev);
        a0.x += ex * bflo(v2.x); a0.y += ex * bfhi(v2.x);
        a0.z += ex * bflo(v2.y); a0.w += ex * bfhi(v2.y);
        a1.x += ex * bflo(v2.z); a1.y += ex * bfhi(v2.z);
        a1.z += ex * bflo(v2.w); a1.w += ex * bfhi(v2.w);
        ssum += ex;
    }
    // ---- tail (deg > 24, ~4% of nodes) ----
    for (k = kbeg + 24 + e8; k < kend; k += 8) {
        const int s = srt_src[k];
        const float al = al1s[s * 8 + hd];
        const uint4 v = *(const uint4*)(xw1b + (long)s * D1 + hd * 8);
        float ev = al + ald; ev = ev > 0.f ? ev : 0.2f * ev;
        const float ex = __expf(ev);
        a0.x += ex * bflo(v.x); a0.y += ex * bfhi(v.x);
        a0.z += ex * bflo(v.y); a0.w += ex * bfhi(v.y);
        a1.x += ex * bflo(v.z); a1.y += ex * bfhi(v.z);
        a1.z += ex * bflo(v.w); a1.w += ex * bfhi(v.w);
        ssum += ex;
    }
    // reduce across the 8 edge slots (lane bits 3,4,5)
#pragma unroll
    for (int mm = 8; mm < 64; mm <<= 1) {
        a0.x += __shfl_xor(a0.x, mm, 64); a0.y += __shfl_xor(a0.y, mm, 64);
        a0.z += __shfl_xor(a0.z, mm, 64); a0.w += __shfl_xor(a0.w, mm, 64);
        a1.x += __shfl_xor(a1.x, mm, 64); a1.y += __shfl_xor(a1.y, mm, 64);
        a1.z += __shfl_xor(a1.z, mm, 64); a1.w += __shfl_xor(a1.w, mm, 64);
        ssum  += __shfl_xor(ssum,  mm, 64);
    }
    const float inv = 1.0f / (ssum + 1e-16f);
    const float4 bb0 = *(const float4*)(b1 + hd * 8);
    const float4 bb1 = *(const float4*)(b1 + hd * 8 + 4);
    float4 r0, r1;
    r0.x = a0.x * inv + bb0.x; r0.x = r0.x > 0.f ? r0.x : expm1f(r0.x);
    r0.y = a0.y * inv + bb0.y; r0.y = r0.y > 0.f ? r0.y : expm1f(r0.y);
    r0.z = a0.z * inv + bb0.z; r0.z = r0.z > 0.f ? r0.z : expm1f(r0.z);
    r0.w = a0.w * inv + bb0.w; r0.w = r0.w > 0.f ? r0.w : expm1f(r0.w);
    r1.x = a1.x * inv + bb1.x; r1.x = r1.x > 0.f ? r1.x : expm1f(r1.x);
    r1.y = a1.y * inv + bb1.y; r1.y = r1.y > 0.f ? r1.y : expm1f(r1.y);
    r1.z = a1.z * inv + bb1.z; r1.z = r1.z > 0.f ? r1.z : expm1f(r1.z);
    r1.w = a1.w * inv + bb1.w; r1.w = r1.w > 0.f ? r1.w : expm1f(r1.w);
    if (e8 == 0) {                          // lanes 0..7: write dims hd*8..hd*8+7
        *(float4*)(&hrow[wid][hd * 8])     = r0;
        *(float4*)(&hrow[wid][hd * 8 + 4]) = r1;
    }
    __syncthreads();                        // w2s fill -> first w2s read
    // layer-2 projection: c split over two 24-lane half-groups
    const int half_ = lane / 24;             // 0,1,2 (lanes 48-63 duplicate half 0)
    const int j2 = lane - half_ * 24;        // 0..23
    const int cb = (half_ == 1) ? 32 : 0;
    float o = 0.f;
#pragma unroll
    for (int c4 = 0; c4 < 8; c4++) {
        const float4 hv = *(const float4*)(&hrow[wid][cb + c4 * 4]);  // broadcast read
        const float* wr = w2s + (cb + c4 * 4) * D2 + j2;
        o += hv.x * wr[0] + hv.y * wr[D2] + hv.z * wr[2 * D2] + hv.w * wr[3 * D2];
    }
    const int src2 = (lane < 24) ? lane + 24 : lane;
    o += __shfl(o, src2, 64);                // lanes<24 hold the full 64-dot
    if (lane < 24) {                         // fp16 head-padded row: [8][4]
        const int h3 = j2 / 3;
        xw2h[(long)n * D2P + h3 * 4 + (j2 - 3 * h3)] = __float2half(o);
    }
    const float ps = o * a2s[j2];
    const float pd = o * a2d[j2];
    const int hb = 3 * (lane & 7);
    const float s3 = __shfl(ps, hb, 64) + __shfl(ps, hb + 1, 64) + __shfl(ps, hb + 2, 64);
    const float d3 = __shfl(pd, hb, 64) + __shfl(pd, hb + 1, 64) + __shfl(pd, hb + 2, 64);
    if (lane < 8) {
        xw2h[(long)n * D2P + lane * 4 + 3] = __float2half(s3);  // src-logit in pad slot
        al2d[n * 8 + lane] = d3;
    }
}

// ============ K4: gather layer 2 + head-mean + softmax ============
// 4 nodes/block, wave-per-node. Batch-3: 3 indices, then 3 uint2 loads (classes
// + logit in one 8B record), then accumulate. Chain depth 1 for deg<=24.
__global__ __launch_bounds__(256) void k_gat2(const int* __restrict__ off,
                                              const int* __restrict__ srt_src,
                                              const float* __restrict__ al2d,
                                              const __half* __restrict__ xw2h,
                                              const float* __restrict__ b2,
                                              float* __restrict__ out) {
    const int tid = threadIdx.x;
    const int lane = tid & 63;
    const int wid = tid >> 6;
    const int n = blockIdx.x * 4 + wid;
    const int e8 = lane >> 3;
    const int hd = lane & 7;

    const float ald = al2d[n * 8 + hd];
    const int kbeg = off[n], kend = off[n + 1];

    float ax = 0.f, ay = 0.f, az = 0.f, ssum = 0.f;
    int k = kbeg + e8;
    const int s0 = (k      < kend) ? srt_src[k]      : -1;
    const int s1 = (k + 8  < kend) ? srt_src[k + 8]  : -1;
    const int s2 = (k + 16 < kend) ? srt_src[k + 16] : -1;
    uint2 v0 = make_uint2(0u, 0u);
    uint2 v1 = make_uint2(0u, 0u);
    uint2 v2 = make_uint2(0u, 0u);
    if (s0 >= 0) v0 = *(const uint2*)(xw2h + (long)s0 * D2P + hd * 4);
    if (s1 >= 0) v1 = *(const uint2*)(xw2h + (long)s1 * D2P + hd * 4);
    if (s2 >= 0) v2 = *(const uint2*)(xw2h + (long)s2 * D2P + hd * 4);
    if (s0 >= 0) {
        const float2 f0 = __half22float2(*(const __half2*)&v0.x);
        const float2 f1 = __half22float2(*(const __half2*)&v0.y);
        float ev = f1.y + ald; ev = ev > 0.f ? ev : 0.2f * ev;
        const float ex = __expf(ev);
        ax += ex * f0.x; ay += ex * f0.y; az += ex * f1.x; ssum += ex;
    }
    if (s1 >= 0) {
        const float2 f0 = __half22float2(*(const __half2*)&v1.x);
        const float2 f1 = __half22float2(*(const __half2*)&v1.y);
        float ev = f1.y + ald; ev = ev > 0.f ? ev : 0.2f * ev;
        const float ex = __expf(ev);
        ax += ex * f0.x; ay += ex * f0.y; az += ex * f1.x; ssum += ex;
    }
    if (s2 >= 0) {
        const float2 f0 = __half22float2(*(const __half2*)&v2.x);
        const float2 f1 = __half22float2(*(const __half2*)&v2.y);
        float ev = f1.y + ald; ev = ev > 0.f ? ev : 0.2f * ev;
        const float ex = __expf(ev);
        ax += ex * f0.x; ay += ex * f0.y; az += ex * f1.x; ssum += ex;
    }
    for (k = kbeg + 24 + e8; k < kend; k += 8) {
        const int s = srt_src[k];
        const uint2 v = *(const uint2*)(xw2h + (long)s * D2P + hd * 4);
        const float2 f0 = __half22float2(*(const __half2*)&v.x);
        const float2 f1 = __half22float2(*(const __half2*)&v.y);
        float ev = f1.y + ald; ev = ev > 0.f ? ev : 0.2f * ev;
        const float ex = __expf(ev);
        ax += ex * f0.x; ay += ex * f0.y; az += ex * f1.x; ssum += ex;
    }
    // reduce across 8 edge slots (bits 3,4,5)
#pragma unroll
    for (int mm = 8; mm < 64; mm <<= 1) {
        ax += __shfl_xor(ax, mm, 64);
        ay += __shfl_xor(ay, mm, 64);
        az += __shfl_xor(az, mm, 64);
        ssum += __shfl_xor(ssum, mm, 64);
    }
    const float inv = 1.0f / (ssum + 1e-16f);
    float mx = ax * inv, my = ay * inv, mz = az * inv;   // this head's alpha-mean
    // head mean: reduce over head bits 0,1,2
#pragma unroll
    for (int mm = 1; mm < 8; mm <<= 1) {
        mx += __shfl_xor(mx, mm, 64);
        my += __shfl_xor(my, mm, 64);
        mz += __shfl_xor(mz, mm, 64);
    }
    const float l0 = mx * 0.125f + b2[0];
    const float l1 = my * 0.125f + b2[1];
    const float l2 = mz * 0.125f + b2[2];
    const float mmax = fmaxf(l0, fmaxf(l1, l2));
    const float ee0 = expf(l0 - mmax), ee1 = expf(l1 - mmax), ee2 = expf(l2 - mmax);
    const float dinv = 1.0f / (ee0 + ee1 + ee2);
    if (lane < 3) {
        const float p = (lane == 0) ? ee0 : (lane == 1) ? ee1 : ee2;
        out[(long)n * 3 + lane] = p * dinv;
    }
}

extern "C" void kernel_launch(void* const* d_in, const int* in_sizes, int n_in,
                              void* d_out, int out_size, void* d_ws, size_t ws_size,
                              hipStream_t stream) {
    const float* x   = (const float*)d_in[0];
    const float* W1  = (const float*)d_in[1];
    const float* a1s = (const float*)d_in[2];
    const float* a1d = (const float*)d_in[3];
    const float* b1  = (const float*)d_in[4];
    const float* W2  = (const float*)d_in[5];
    const float* a2s = (const float*)d_in[6];
    const float* a2d = (const float*)d_in[7];
    const float* b2  = (const float*)d_in[8];
    const int*   ei  = (const int*)d_in[9];
    float* out = (float*)d_out;

    float* ws    = (float*)d_ws;
    float* al1s  = ws;                        //   800,000
    float* al1d  = al1s + 800000;             //   800,000
    float* al2d  = al1d + 800000;             //   800,000
    short* xw1b  = (short*)(al2d + 800000);   // 6,400,000 shorts (bf16)
    __half* xw2h = (__half*)(xw1b + 6400000); // 3,200,000 halfs (fp16)
    int* off     = (int*)(xw2h + 3200000);    //   100,004
    int* gcnt    = off + 100004;              //   391*32 line-padded cursors
    int* srt     = gcnt + NBKT * 32;          // 1,700,000
    short* wT    = (short*)(srt + 1700000);   //   64*512 halfs (16B aligned)
    int* tmp     = (int*)(wT + 32768);        //   391*5120 = 2,001,920 ints

    k_init<<<64, 256, 0, stream>>>(gcnt, W1, wT);
    k_pg<<<NPB + GEMB, 256, 0, stream>>>(ei, gcnt, tmp, x, wT, a1s, a1d,
                                         xw1b, al1s, al1d);
    k_bucket2<<<NBKT, 512, 0, stream>>>(gcnt, tmp, off, srt);
    k_gat1<<<N_NODESC / 8, 512, 0, stream>>>(off, srt, al1s, al1d, xw1b, b1,
                                             W2, a2s, a2d, xw2h, al2d);
    k_gat2<<<N_NODESC / 4, 256, 0, stream>>>(off, srt, al2d, xw2h, b2, out);
}